// Round 1
// baseline (725.844 us; speedup 1.0000x reference)
//
#include <hip/hip_runtime.h>
#include <hip/hip_fp16.h>

namespace {

constexpr int kB = 128;     // batch
constexpr int kI = 1152;    // input capsules
constexpr int kD = 8;       // input dim
constexpr int kN = 32;      // output capsules
constexpr int kE = 16;      // output dim
constexpr int kCI = 4;      // input capsules per chunk
constexpr int kNC = kI / kCI;  // 288 chunks
constexpr int kBlk = 128;   // threads per pass block (2 waves)

constexpr size_t kPartBytes = (size_t)kNC * kB * kN * kE * 2;  // 37,748,736 B fp16

__device__ __forceinline__ void load16(const float* __restrict__ p, float* r) {
  const float4* p4 = reinterpret_cast<const float4*>(p);
  float4 a = p4[0], b = p4[1], c = p4[2], d = p4[3];
  r[0]=a.x; r[1]=a.y; r[2]=a.z;  r[3]=a.w;
  r[4]=b.x; r[5]=b.y; r[6]=b.z;  r[7]=b.w;
  r[8]=c.x; r[9]=c.y; r[10]=c.z; r[11]=c.w;
  r[12]=d.x; r[13]=d.y; r[14]=d.z; r[15]=d.w;
}

// One routing iteration's "S pass": logits = bias (+ <u_hat, vsum> if PASS>0),
// softmax over n, partial s = sum_{i in chunk} c * u_hat  (u_hat recomputed).
// Lanes map to batch -> W reads are wave-broadcast.
template<int PASS>
__global__ __launch_bounds__(kBlk)
void caps_pass(const float* __restrict__ x, const float* __restrict__ W,
               const float* __restrict__ bias, const float* __restrict__ vsum,
               __half* __restrict__ part)
{
  // per-thread logit/softmax scratch; runtime-ns indexed -> LDS, not scratch
  __shared__ __half cwl[kCI][16][kBlk];

  const int chunk = blockIdx.x;
  const int i0 = chunk * kCI;
  const int tid = (int)threadIdx.x;
  const int wave = tid >> 6;
  const int bl = tid & 31;
  const int h = (tid >> 5) & 1;                 // n-half within wave
  const int b = (int)blockIdx.y * 64 + wave * 32 + bl;

  // x[b][i0+i][*] into registers
  float xr[kCI][kD];
#pragma unroll
  for (int i = 0; i < kCI; ++i) {
    const float4* xp = reinterpret_cast<const float4*>(
        x + (size_t)b * (kI * kD) + (size_t)(i0 + i) * kD);
    float4 a = xp[0], c = xp[1];
    xr[i][0]=a.x; xr[i][1]=a.y; xr[i][2]=a.z; xr[i][3]=a.w;
    xr[i][4]=c.x; xr[i][5]=c.y; xr[i][6]=c.z; xr[i][7]=c.w;
  }

  // init logits with bias
#pragma unroll
  for (int i = 0; i < kCI; ++i) {
    float brow[16];
    load16(bias + (size_t)(i0 + i) * kN + h * 16, brow);
#pragma unroll
    for (int ns = 0; ns < 16; ++ns) cwl[i][ns][tid] = __float2half(brow[ns]);
  }

  if (PASS > 0) {
    // logits += sum_e u_hat[e]*vsum[e] = sum_d x_d * (sum_e W[d][e]*vsum[e])
#pragma unroll 1
    for (int ns = 0; ns < 16; ++ns) {
      const int n = h * 16 + ns;
      float vs[16];
      load16(vsum + ((size_t)b * kN + n) * kE, vs);
#pragma unroll
      for (int i = 0; i < kCI; ++i) {
        const float* wb = W + (size_t)(i0 + i) * (kN * kD * kE) + (size_t)n * (kD * kE);
        float dot = 0.f;
#pragma unroll
        for (int d = 0; d < kD; ++d) {
          float wrow[16];
          load16(wb + d * kE, wrow);
          float t = 0.f;
#pragma unroll
          for (int e = 0; e < kE; ++e) t += wrow[e] * vs[e];
          dot += xr[i][d] * t;
        }
        cwl[i][ns][tid] = __float2half(__half2float(cwl[i][ns][tid]) + dot);
      }
    }
  }

  // softmax over n per (b,i): 16 local + other half via shfl_xor(32)
  float invs[kCI];
#pragma unroll
  for (int i = 0; i < kCI; ++i) {
    float m = -1e30f;
#pragma unroll
    for (int ns = 0; ns < 16; ++ns) m = fmaxf(m, __half2float(cwl[i][ns][tid]));
    m = fmaxf(m, __shfl_xor(m, 32, 64));
    float ssum = 0.f;
#pragma unroll
    for (int ns = 0; ns < 16; ++ns) {
      float ev = __expf(__half2float(cwl[i][ns][tid]) - m);
      ssum += ev;
      cwl[i][ns][tid] = __float2half(ev);
    }
    ssum += __shfl_xor(ssum, 32, 64);
    invs[i] = 1.f / ssum;
  }

  // partial s = sum_{i in chunk} c * u_hat   (recompute u_hat)
#pragma unroll 1
  for (int ns = 0; ns < 16; ++ns) {
    const int n = h * 16 + ns;
    float acc[kE];
#pragma unroll
    for (int e = 0; e < kE; ++e) acc[e] = 0.f;
#pragma unroll
    for (int i = 0; i < kCI; ++i) {
      const float cc = __half2float(cwl[i][ns][tid]) * invs[i];
      const float* wb = W + (size_t)(i0 + i) * (kN * kD * kE) + (size_t)n * (kD * kE);
#pragma unroll
      for (int d = 0; d < kD; ++d) {
        float wrow[16];
        load16(wb + d * kE, wrow);
        const float cx = cc * xr[i][d];
#pragma unroll
        for (int e = 0; e < kE; ++e) acc[e] += cx * wrow[e];
      }
    }
    __half hp[16];
#pragma unroll
    for (int e = 0; e < kE; ++e) hp[e] = __float2half(acc[e]);
    __half* dst = part + (((size_t)chunk * kB + b) * kN + n) * kE;
    reinterpret_cast<int4*>(dst)[0] = reinterpret_cast<const int4*>(hp)[0];
    reinterpret_cast<int4*>(dst)[1] = reinterpret_cast<const int4*>(hp)[1];
  }
}

// Reduce partials over chunks, squash; MODE 0: vsum = v; 1: vsum += v; 2: out = v
template<int MODE>
__global__ __launch_bounds__(128)
void caps_reduce(const __half* __restrict__ part, float* __restrict__ vsum,
                 float* __restrict__ out)
{
  const int b = blockIdx.x;
  const int tid = (int)threadIdx.x;
  const int ne = (int)blockIdx.y * 256 + tid * 2;   // [0,512) within (n,e)
  const __half* p = part + (size_t)b * (kN * kE) + ne;
  float ax = 0.f, ay = 0.f;
  for (int ch = 0; ch < kNC; ++ch) {
    __half2 hv = *reinterpret_cast<const __half2*>(p + (size_t)ch * (kB * kN * kE));
    float2 f = __half22float2(hv);
    ax += f.x; ay += f.y;
  }
  // squash: |s|^2 over the 8 lanes (16 e) sharing this n
  float s2 = ax * ax + ay * ay;
  s2 += __shfl_xor(s2, 1, 64);
  s2 += __shfl_xor(s2, 2, 64);
  s2 += __shfl_xor(s2, 4, 64);
  const float scale = (s2 / (1.f + s2)) * rsqrtf(fmaxf(s2, 1e-30f));
  float2 v = make_float2(ax * scale, ay * scale);
  const size_t o = (size_t)b * (kN * kE) + ne;
  if (MODE == 2) {
    *reinterpret_cast<float2*>(out + o) = v;
  } else if (MODE == 1) {
    float2 old = *reinterpret_cast<const float2*>(vsum + o);
    v.x += old.x; v.y += old.y;
    *reinterpret_cast<float2*>(vsum + o) = v;
  } else {
    *reinterpret_cast<float2*>(vsum + o) = v;
  }
}

}  // namespace

extern "C" void kernel_launch(void* const* d_in, const int* in_sizes, int n_in,
                              void* d_out, int out_size, void* d_ws, size_t ws_size,
                              hipStream_t stream) {
  (void)in_sizes; (void)n_in; (void)out_size; (void)ws_size;
  const float* x    = reinterpret_cast<const float*>(d_in[0]);
  const float* W    = reinterpret_cast<const float*>(d_in[1]);
  const float* bias = reinterpret_cast<const float*>(d_in[2]);
  float* out = reinterpret_cast<float*>(d_out);

  __half* part = reinterpret_cast<__half*>(d_ws);
  float* vsum  = reinterpret_cast<float*>(reinterpret_cast<char*>(d_ws) + kPartBytes);

  dim3 pg(kNC, 2), pb(kBlk);
  dim3 rg(kB, 2), rb(128);

  // iter 0: logits = bias; v0 -> vsum
  caps_pass<0><<<pg, pb, 0, stream>>>(x, W, bias, vsum, part);
  caps_reduce<0><<<rg, rb, 0, stream>>>(part, vsum, out);
  // iter 1: logits = bias + <u_hat, v0>; vsum += v1
  caps_pass<1><<<pg, pb, 0, stream>>>(x, W, bias, vsum, part);
  caps_reduce<1><<<rg, rb, 0, stream>>>(part, vsum, out);
  // iter 2: logits = bias + <u_hat, v0+v1>; out = squash(s)
  caps_pass<2><<<pg, pb, 0, stream>>>(x, W, bias, vsum, part);
  caps_reduce<2><<<rg, rb, 0, stream>>>(part, vsum, out);
}

// Round 2
// 332.254 us; speedup vs baseline: 2.1846x; 2.1846x over previous
//
#include <hip/hip_runtime.h>
#include <hip/hip_fp16.h>

namespace {

constexpr int kB = 128, kI = 1152, kD = 8, kN = 32, kE = 16;
constexpr int kTI = 4;               // input capsules per chunk
constexpr int kNC = kI / kTI;        // 288 chunks
constexpr int kBlk = 128;            // 2 waves: 64 b-slots x 2 n-halves

constexpr size_t kPartBytes = (size_t)kNC * kN * kB * kE * 2;  // 37,748,736 B

typedef _Float16 h2v __attribute__((ext_vector_type(2)));

__device__ __forceinline__ float fdot2(__half2 a, __half2 b, float c) {
#if defined(__has_builtin) && __has_builtin(__builtin_amdgcn_fdot2)
  return __builtin_amdgcn_fdot2(__builtin_bit_cast(h2v, a),
                                __builtin_bit_cast(h2v, b), c, false);
#else
  float2 af = __half22float2(a), bf = __half22float2(b);
  return fmaf(af.y, bf.y, fmaf(af.x, bf.x, c));
#endif
}

union I4H { int4 v; __half2 h[4]; };

// One routing iteration: logits = bias (+ <u_hat, vsum>), softmax over n,
// partial s = sum_{i in chunk} c * u_hat. u_hat recomputed from fp16 W (LDS)
// and broadcast-half2 x (regs) via packed fp16 FMA. Lanes = batch -> all W
// reads are wave-broadcast (conflict-free).
template<int PASS>
__global__ __launch_bounds__(kBlk)
void caps_pass(const float* __restrict__ x, const float* __restrict__ W,
               const float* __restrict__ bias, const __half* __restrict__ vsh,
               __half* __restrict__ part)
{
  __shared__ __half2 wlds[kTI * kN * kD * kE / 2];  // 8192 h2 = 32 KB
  __shared__ __half  llds[kTI * 16 * kBlk];         // 16 KB, thread-private slots

  const int chunk = blockIdx.x;
  const int i0 = chunk * kTI;
  const int tid = (int)threadIdx.x;
  const int h = (tid >> 5) & 1;
  const int b = (int)blockIdx.y * 64 + (tid >> 6) * 32 + (tid & 31);

  // stage W chunk (64 KB fp32) -> 32 KB fp16 LDS, coalesced + conflict-free
  {
    const float2* src2 = reinterpret_cast<const float2*>(W + (size_t)i0 * (kN * kD * kE));
#pragma unroll
    for (int k = 0; k < 64; ++k)
      wlds[k * kBlk + tid] = __float22half2_rn(src2[k * kBlk + tid]);
  }
  __syncthreads();

  // x rows -> broadcast half2 registers
  __half2 x2[kTI][kD];
#pragma unroll
  for (int i = 0; i < kTI; ++i) {
    const float4* xp = reinterpret_cast<const float4*>(
        x + (size_t)b * (kI * kD) + (size_t)(i0 + i) * kD);
    float4 a = xp[0], c = xp[1];
    float xf[8] = {a.x, a.y, a.z, a.w, c.x, c.y, c.z, c.w};
#pragma unroll
    for (int d = 0; d < kD; ++d) x2[i][d] = __half2half2(__float2half_rn(xf[d]));
  }

  // ---- phase 1: logits -> llds (thread-private slots, no barrier needed) ----
#pragma unroll 1
  for (int ns = 0; ns < 16; ++ns) {
    const int n = h * 16 + ns;
    if (PASS == 0) {
#pragma unroll
      for (int i = 0; i < kTI; ++i)
        llds[(i * 16 + ns) * kBlk + tid] = __float2half(bias[(size_t)(i0 + i) * kN + n]);
    } else {
      I4H va, vb;
      const int4* vp = reinterpret_cast<const int4*>(vsh + ((size_t)b * kN + n) * kE);
      va.v = vp[0]; vb.v = vp[1];
#pragma unroll
      for (int i = 0; i < kTI; ++i) {
        const int4* wp = reinterpret_cast<const int4*>(
            wlds + (size_t)(i * kN + n) * kD * (kE / 2));
        __half2 uh[8];
#pragma unroll
        for (int d = 0; d < kD; ++d) {
          I4H wa, wb; wa.v = wp[2 * d]; wb.v = wp[2 * d + 1];
          if (d == 0) {
#pragma unroll
            for (int e = 0; e < 4; ++e) {
              uh[e]     = __hmul2(x2[i][0], wa.h[e]);
              uh[4 + e] = __hmul2(x2[i][0], wb.h[e]);
            }
          } else {
#pragma unroll
            for (int e = 0; e < 4; ++e) {
              uh[e]     = __hfma2(x2[i][d], wa.h[e], uh[e]);
              uh[4 + e] = __hfma2(x2[i][d], wb.h[e], uh[4 + e]);
            }
          }
        }
        float lg = bias[(size_t)(i0 + i) * kN + n];
#pragma unroll
        for (int e = 0; e < 4; ++e) {
          lg = fdot2(uh[e],     va.h[e], lg);
          lg = fdot2(uh[4 + e], vb.h[e], lg);
        }
        llds[(i * 16 + ns) * kBlk + tid] = __float2half(lg);
      }
    }
  }

  // ---- softmax over n per (b,i): 16 local + partner half via shfl_xor(32) ----
  float invs[kTI];
#pragma unroll
  for (int i = 0; i < kTI; ++i) {
    float m = -1e30f;
#pragma unroll
    for (int ns = 0; ns < 16; ++ns)
      m = fmaxf(m, __half2float(llds[(i * 16 + ns) * kBlk + tid]));
    m = fmaxf(m, __shfl_xor(m, 32, 64));
    float s = 0.f;
#pragma unroll
    for (int ns = 0; ns < 16; ++ns) {
      float ev = __expf(__half2float(llds[(i * 16 + ns) * kBlk + tid]) - m);
      s += ev;
      llds[(i * 16 + ns) * kBlk + tid] = __float2half(ev);
    }
    s += __shfl_xor(s, 32, 64);
    invs[i] = 1.f / s;
  }

  // ---- phase 2: partial s = sum_i c * u_hat (u_hat recomputed, c folded into x) ----
#pragma unroll 1
  for (int ns = 0; ns < 16; ++ns) {
    const int n = h * 16 + ns;
    __half2 acc[8];
#pragma unroll
    for (int e = 0; e < 8; ++e) acc[e] = __half2half2(__float2half(0.f));
#pragma unroll
    for (int i = 0; i < kTI; ++i) {
      const float cf = __half2float(llds[(i * 16 + ns) * kBlk + tid]) * invs[i];
      const __half2 c2 = __half2half2(__float2half_rn(cf));
      const int4* wp = reinterpret_cast<const int4*>(
          wlds + (size_t)(i * kN + n) * kD * (kE / 2));
#pragma unroll
      for (int d = 0; d < kD; ++d) {
        I4H wa, wb; wa.v = wp[2 * d]; wb.v = wp[2 * d + 1];
        const __half2 cx = __hmul2(c2, x2[i][d]);
#pragma unroll
        for (int e = 0; e < 4; ++e) {
          acc[e]     = __hfma2(cx, wa.h[e], acc[e]);
          acc[4 + e] = __hfma2(cx, wb.h[e], acc[4 + e]);
        }
      }
    }
    I4H oa, ob;
#pragma unroll
    for (int e = 0; e < 4; ++e) { oa.h[e] = acc[e]; ob.h[e] = acc[4 + e]; }
    // part[ch][n][b][e]: lanes b-consecutive -> contiguous 1 KB per half-wave
    int4* dst = reinterpret_cast<int4*>(part + (((size_t)chunk * kN + n) * kB + b) * kE);
    dst[0] = oa.v; dst[1] = ob.v;
  }
}

// Reduce partials over chunks, squash. MODE 0: vsum=v; 1: vsum+=v; 2: out=v.
// vsh (half copy of vsum) is what the pass kernels consume.
template<int MODE>
__global__ __launch_bounds__(128)
void caps_reduce(const __half* __restrict__ part, float* __restrict__ vsum,
                 __half* __restrict__ vsh, float* __restrict__ out)
{
  const int b = (int)blockIdx.x;
  const int tid = (int)threadIdx.x;
  const int nl = tid >> 3, ep = tid & 7;
  const int n = (int)blockIdx.y * 16 + nl;

  const __half2* p = reinterpret_cast<const __half2*>(part) +
                     (((size_t)n * kB + b) * kE + ep * 2) / 2;
  constexpr size_t chStride = (size_t)kN * kB * kE / 2;
  float ax = 0.f, ay = 0.f;
#pragma unroll 4
  for (int ch = 0; ch < kNC; ++ch) {
    float2 f = __half22float2(p[(size_t)ch * chStride]);
    ax += f.x; ay += f.y;
  }
  float s2 = ax * ax + ay * ay;
  s2 += __shfl_xor(s2, 1, 64);
  s2 += __shfl_xor(s2, 2, 64);
  s2 += __shfl_xor(s2, 4, 64);
  const float sc = (s2 / (1.f + s2)) * rsqrtf(fmaxf(s2, 1e-30f));
  float vx = ax * sc, vy = ay * sc;
  const size_t o = ((size_t)b * kN + n) * kE + ep * 2;
  if (MODE == 2) {
    *reinterpret_cast<float2*>(out + o) = make_float2(vx, vy);
  } else {
    if (MODE == 1) {
      float2 old = *reinterpret_cast<const float2*>(vsum + o);
      vx += old.x; vy += old.y;
    }
    *reinterpret_cast<float2*>(vsum + o) = make_float2(vx, vy);
    *reinterpret_cast<__half2*>(vsh + o) = __floats2half2_rn(vx, vy);
  }
}

}  // namespace

extern "C" void kernel_launch(void* const* d_in, const int* in_sizes, int n_in,
                              void* d_out, int out_size, void* d_ws, size_t ws_size,
                              hipStream_t stream) {
  (void)in_sizes; (void)n_in; (void)out_size; (void)ws_size;
  const float* x    = reinterpret_cast<const float*>(d_in[0]);
  const float* W    = reinterpret_cast<const float*>(d_in[1]);
  const float* bias = reinterpret_cast<const float*>(d_in[2]);
  float* out = reinterpret_cast<float*>(d_out);

  __half* part = reinterpret_cast<__half*>(d_ws);
  float*  vsum = reinterpret_cast<float*>(reinterpret_cast<char*>(d_ws) + kPartBytes);
  __half* vsh  = reinterpret_cast<__half*>(reinterpret_cast<char*>(d_ws) + kPartBytes +
                                           (size_t)kB * kN * kE * 4);

  dim3 pg(kNC, 2), pb(kBlk);
  dim3 rg(kB, 2), rb(128);

  // iter 0: logits = bias; v0 -> vsum/vsh
  caps_pass<0><<<pg, pb, 0, stream>>>(x, W, bias, vsh, part);
  caps_reduce<0><<<rg, rb, 0, stream>>>(part, vsum, vsh, out);
  // iter 1: logits = bias + <u_hat, v0>; vsum += v1
  caps_pass<1><<<pg, pb, 0, stream>>>(x, W, bias, vsh, part);
  caps_reduce<1><<<rg, rb, 0, stream>>>(part, vsum, vsh, out);
  // iter 2: logits = bias + <u_hat, v0+v1>; out = squash(s)
  caps_pass<2><<<pg, pb, 0, stream>>>(x, W, bias, vsh, part);
  caps_reduce<2><<<rg, rb, 0, stream>>>(part, vsum, vsh, out);
}

// Round 3
// 204.923 us; speedup vs baseline: 3.5420x; 1.6214x over previous
//
#include <hip/hip_runtime.h>
#include <hip/hip_fp16.h>

namespace {

constexpr int kB = 128, kI = 1152, kD = 8, kN = 32, kE = 16;
constexpr int kTI = 4;                 // input capsules per chunk
constexpr int kNC = kI / kTI;          // 288 chunks
constexpr int kCG = 4;                 // chunk groups for 2-level reduce
constexpr int kCPG = kNC / kCG;        // 72 chunks per group

constexpr size_t kPartBytes = (size_t)kNC * kB * kN * kE * 2;      // 36.9 MB fp16
constexpr size_t kPart2Bytes = (size_t)kCG * kB * kN * kE * 4;     // 1 MB f32
constexpr size_t kVsumBytes = (size_t)kB * kN * kE * 4;            // 256 KB f32
// vsh: fp16 copy of vsum, 128 KB

typedef _Float16 h2v __attribute__((ext_vector_type(2)));

__device__ __forceinline__ float fdot2(__half2 a, __half2 b, float c) {
#if defined(__has_builtin) && __has_builtin(__builtin_amdgcn_fdot2)
  return __builtin_amdgcn_fdot2(__builtin_bit_cast(h2v, a),
                                __builtin_bit_cast(h2v, b), c, false);
#else
  float2 af = __half22float2(a), bf = __half22float2(b);
  return fmaf(af.y, bf.y, fmaf(af.x, bf.x, c));
#endif
}

union I4H { int4 v; __half2 h[4]; };

// Routing pass. Lanes = (eh, n): eh = e-octet (2), n = out-capsule (32).
// W chunk (4 i) lives in 128 VGPRs per lane, loaded once via LDS transpose.
// Each of 4 waves handles 8 batches; softmax over n via shfl_xor.
template<int PASS>
__global__ __launch_bounds__(256, 2)
void caps_pass(const float* __restrict__ x, const float* __restrict__ W,
               const float* __restrict__ bias, const __half* __restrict__ vsh,
               __half* __restrict__ part)
{
  __shared__ __half2 wlds[kTI * kD * 64 * 4];  // [(i*8+d)*64+lane][quad], 32 KB
  __shared__ __half2 xlds[32][kTI * kD];       // dup half2 per (b-local, i*8+d), 4 KB

  const int chunk = (int)blockIdx.x;
  const int i0 = chunk * kTI;
  const int b0 = (int)blockIdx.y * 32;
  const int t = (int)threadIdx.x;
  const int lane = t & 63;
  const int wv = t >> 6;
  const int eh = lane >> 5;   // e-octet
  const int n  = lane & 31;   // out capsule

  // ---- stage W chunk (16384 f32) -> transposed fp16 LDS ----
  {
    const float2* wsrc = reinterpret_cast<const float2*>(
        W + (size_t)chunk * (kTI * kN * kD * kE));
    const int e  = (t * 2) & 15;
    const int dd = ((t * 2) >> 4) & 7;
    const int ehw = e >> 3, ep = (e & 7) >> 1;
#pragma unroll
    for (int iter = 0; iter < 32; ++iter) {
      const int nn_i = iter * 4 + (t >> 6);   // = f/128
      const int nn = nn_i & 31, ii = nn_i >> 5;
      float2 f2 = wsrc[iter * 256 + t];
      wlds[((ii * kD + dd) * 64 + ehw * 32 + nn) * 4 + ep] =
          __floats2half2_rn(f2.x, f2.y);
    }
  }
  // ---- stage x tile: 32 b x (4 i x 8 d), duplicated half2 ----
  {
    const int r = t >> 3, c = (t & 7) * 4;
    const float4 f4 = *reinterpret_cast<const float4*>(
        x + (size_t)(b0 + r) * (kI * kD) + i0 * kD + c);
    xlds[r][c + 0] = __half2half2(__float2half_rn(f4.x));
    xlds[r][c + 1] = __half2half2(__float2half_rn(f4.y));
    xlds[r][c + 2] = __half2half2(__float2half_rn(f4.z));
    xlds[r][c + 3] = __half2half2(__float2half_rn(f4.w));
  }
  __syncthreads();

  // ---- W chunk into registers: wr[i][d][quad] (conflict-free b128 reads) ----
  __half2 wr[kTI][kD][4];
#pragma unroll
  for (int i = 0; i < kTI; ++i)
#pragma unroll
    for (int d = 0; d < kD; ++d) {
      I4H q; q.v = *reinterpret_cast<const int4*>(&wlds[((i * kD + d) * 64 + lane) * 4]);
#pragma unroll
      for (int k = 0; k < 4; ++k) wr[i][d][k] = q.h[k];
    }

  float bf[kTI];
#pragma unroll
  for (int i = 0; i < kTI; ++i) bf[i] = bias[(size_t)(i0 + i) * kN + n];

  // PASS 0: coupling c depends only on (i, n) -> softmax once, outside b-loop
  __half2 c0[kTI];
  if (PASS == 0) {
#pragma unroll
    for (int i = 0; i < kTI; ++i) {
      float lg = bf[i];
      float m = lg;
#pragma unroll
      for (int o = 1; o <= 16; o <<= 1) m = fmaxf(m, __shfl_xor(m, o, 64));
      float ev = __expf(lg - m);
      float sm = ev;
#pragma unroll
      for (int o = 1; o <= 16; o <<= 1) sm += __shfl_xor(sm, o, 64);
      c0[i] = __half2half2(__float2half_rn(ev / sm));
    }
  }

#pragma unroll 2
  for (int bb = 0; bb < 8; ++bb) {
    const int bl = wv * 8 + bb;
    const int b = b0 + bl;
    I4H vq;
    if (PASS > 0)
      vq.v = *reinterpret_cast<const int4*>(vsh + ((size_t)b * kN + n) * kE + eh * 8);

    __half2 s[4];
#pragma unroll
    for (int k = 0; k < 4; ++k) s[k] = __half2half2(__float2half(0.f));

#pragma unroll
    for (int i = 0; i < kTI; ++i) {
      I4H xa, xb;
      xa.v = *reinterpret_cast<const int4*>(&xlds[bl][i * kD]);
      xb.v = *reinterpret_cast<const int4*>(&xlds[bl][i * kD + 4]);
      __half2 uh[4];
#pragma unroll
      for (int k = 0; k < 4; ++k) uh[k] = __hmul2(xa.h[0], wr[i][0][k]);
#pragma unroll
      for (int d = 1; d < 4; ++d)
#pragma unroll
        for (int k = 0; k < 4; ++k) uh[k] = __hfma2(xa.h[d], wr[i][d][k], uh[k]);
#pragma unroll
      for (int d = 0; d < 4; ++d)
#pragma unroll
        for (int k = 0; k < 4; ++k) uh[k] = __hfma2(xb.h[d], wr[i][4 + d][k], uh[k]);

      __half2 c2;
      if (PASS == 0) {
        c2 = c0[i];
      } else {
        float lg = bf[i];
#pragma unroll
        for (int k = 0; k < 4; ++k) lg = fdot2(uh[k], vq.h[k], lg);
        lg += __shfl_xor(lg, 32, 64);           // sum both e-octets
        float m = lg;
#pragma unroll
        for (int o = 1; o <= 16; o <<= 1) m = fmaxf(m, __shfl_xor(m, o, 64));
        float ev = __expf(lg - m);
        float sm = ev;
#pragma unroll
        for (int o = 1; o <= 16; o <<= 1) sm += __shfl_xor(sm, o, 64);
        c2 = __half2half2(__float2half_rn(ev / sm));
      }
#pragma unroll
      for (int k = 0; k < 4; ++k) s[k] = __hfma2(c2, uh[k], s[k]);
    }
    I4H o;
#pragma unroll
    for (int k = 0; k < 4; ++k) o.h[k] = s[k];
    *reinterpret_cast<int4*>(
        part + (((size_t)chunk * kB + b) * kN + n) * kE + eh * 8) = o.v;
  }
}

// Level-1 reduce: sum 72 chunks of fp16 partials -> f32 partial2[cg][b][n][e]
__global__ __launch_bounds__(256)
void caps_reduce1(const __half* __restrict__ part, float* __restrict__ partial2)
{
  const int b = (int)blockIdx.x, cg = (int)blockIdx.y;
  const int t = (int)threadIdx.x;
  const int nl = t >> 3, ep = t & 7;
  const __half2* p = reinterpret_cast<const __half2*>(
      part + (((size_t)(cg * kCPG) * kB + b) * kN + nl) * kE + ep * 2);
  const size_t stride = (size_t)kB * kN * kE / 2;  // half2 per chunk
  float ax = 0.f, ay = 0.f;
#pragma unroll 8
  for (int ch = 0; ch < kCPG; ++ch) {
    float2 f = __half22float2(p[(size_t)ch * stride]);
    ax += f.x; ay += f.y;
  }
  *reinterpret_cast<float2*>(
      partial2 + (((size_t)cg * kB + b) * kN + nl) * kE + ep * 2) = make_float2(ax, ay);
}

// Final: sum 4 chunk-groups, squash. MODE 0: vsum=v,vsh=v; 1: vsum+=v; 2: out=v.
template<int MODE>
__global__ __launch_bounds__(256)
void caps_final(const float* __restrict__ partial2, float* __restrict__ vsum,
                __half* __restrict__ vsh, float* __restrict__ out)
{
  const int b = (int)blockIdx.x;
  const int t = (int)threadIdx.x;
  const int nl = t >> 3, ep = t & 7;
  const size_t o = ((size_t)b * kN + nl) * kE + ep * 2;
  float ax = 0.f, ay = 0.f;
#pragma unroll
  for (int cg = 0; cg < kCG; ++cg) {
    float2 f = *reinterpret_cast<const float2*>(
        partial2 + (size_t)cg * kB * kN * kE + o);
    ax += f.x; ay += f.y;
  }
  float s2 = ax * ax + ay * ay;
  s2 += __shfl_xor(s2, 1, 64);
  s2 += __shfl_xor(s2, 2, 64);
  s2 += __shfl_xor(s2, 4, 64);
  const float sc = (s2 / (1.f + s2)) * rsqrtf(fmaxf(s2, 1e-30f));
  float vx = ax * sc, vy = ay * sc;
  if (MODE == 2) {
    *reinterpret_cast<float2*>(out + o) = make_float2(vx, vy);
  } else {
    if (MODE == 1) {
      float2 old = *reinterpret_cast<const float2*>(vsum + o);
      vx += old.x; vy += old.y;
    }
    *reinterpret_cast<float2*>(vsum + o) = make_float2(vx, vy);
    *reinterpret_cast<__half2*>(vsh + o) = __floats2half2_rn(vx, vy);
  }
}

}  // namespace

extern "C" void kernel_launch(void* const* d_in, const int* in_sizes, int n_in,
                              void* d_out, int out_size, void* d_ws, size_t ws_size,
                              hipStream_t stream) {
  (void)in_sizes; (void)n_in; (void)out_size; (void)ws_size;
  const float* x    = reinterpret_cast<const float*>(d_in[0]);
  const float* W    = reinterpret_cast<const float*>(d_in[1]);
  const float* bias = reinterpret_cast<const float*>(d_in[2]);
  float* out = reinterpret_cast<float*>(d_out);

  char* ws = reinterpret_cast<char*>(d_ws);
  __half* part     = reinterpret_cast<__half*>(ws);
  float*  partial2 = reinterpret_cast<float*>(ws + kPartBytes);
  float*  vsum     = reinterpret_cast<float*>(ws + kPartBytes + kPart2Bytes);
  __half* vsh      = reinterpret_cast<__half*>(ws + kPartBytes + kPart2Bytes + kVsumBytes);

  dim3 pg(kNC, kB / 32), pb(256);
  dim3 rg(kB, kCG), rb(256);

  // iter 0: c = softmax(bias); v0 -> vsum/vsh
  caps_pass<0><<<pg, pb, 0, stream>>>(x, W, bias, vsh, part);
  caps_reduce1<<<rg, rb, 0, stream>>>(part, partial2);
  caps_final<0><<<kB, 256, 0, stream>>>(partial2, vsum, vsh, out);
  // iter 1: logits = bias + <u_hat, v0>; vsum += v1
  caps_pass<1><<<pg, pb, 0, stream>>>(x, W, bias, vsh, part);
  caps_reduce1<<<rg, rb, 0, stream>>>(part, partial2);
  caps_final<1><<<kB, 256, 0, stream>>>(partial2, vsum, vsh, out);
  // iter 2: logits = bias + <u_hat, v0+v1>; out = squash(s)
  caps_pass<2><<<pg, pb, 0, stream>>>(x, W, bias, vsh, part);
  caps_reduce1<<<rg, rb, 0, stream>>>(part, partial2);
  caps_final<2><<<kB, 256, 0, stream>>>(partial2, vsum, vsh, out);
}